// Round 10
// baseline (529.188 us; speedup 1.0000x reference)
//
#include <hip/hip_runtime.h>
#include <math.h>

#define BB 4
#define SS 2048
#define DDM 1024
#define HH 16
#define MM (BB * SS)  // 8192

typedef _Float16 f16;
typedef f16 half8 __attribute__((ext_vector_type(8)));
typedef f16 f16x4 __attribute__((ext_vector_type(4)));
typedef float f32x4 __attribute__((ext_vector_type(4)));

#define GLOAD16(g, l)                                                  \
  __builtin_amdgcn_global_load_lds(                                    \
      (const __attribute__((address_space(1))) void*)(g),              \
      (__attribute__((address_space(3))) void*)(l), 16, 0, 0)

// ---------------------------------------------------------------------------
// fp32 -> f16 convert, all three activations in one launch (blockIdx.y picks)
// ---------------------------------------------------------------------------
__global__ void cvt3_k(const float* __restrict__ q, const float* __restrict__ k,
                       const float* __restrict__ v, f16* __restrict__ oq,
                       f16* __restrict__ ok, f16* __restrict__ ov, int n4) {
  const float* in = (blockIdx.y == 0) ? q : (blockIdx.y == 1) ? k : v;
  f16* out = (blockIdx.y == 0) ? oq : (blockIdx.y == 1) ? ok : ov;
  int i = blockIdx.x * blockDim.x + threadIdx.x;
  const int stride = gridDim.x * blockDim.x;
  for (; i < n4; i += stride) {
    const float4 t = reinterpret_cast<const float4*>(in)[i];
    f16x4 o;
    o.x = (f16)t.x; o.y = (f16)t.y; o.z = (f16)t.z; o.w = (f16)t.w;
    reinterpret_cast<f16x4*>(out)[i] = o;
  }
}

// ---------------------------------------------------------------------------
// All 4 weights: W [1024][1024] fp32 -> W^T f16, one launch (blockIdx.z picks)
// Wt_all layout: [4][1024][1024] (q,k,v,o)
// ---------------------------------------------------------------------------
__global__ void wtr4_k(const float* __restrict__ Wq, const float* __restrict__ Wk,
                       const float* __restrict__ Wv, const float* __restrict__ Wo,
                       f16* __restrict__ Wt_all) {
  __shared__ float t[32][33];
  const int z = blockIdx.z;
  const float* W = (z == 0) ? Wq : (z == 1) ? Wk : (z == 2) ? Wv : Wo;
  f16* Wt = Wt_all + (size_t)z * DDM * DDM;
  const int bx = blockIdx.x * 32, by = blockIdx.y * 32;
  const int tx = threadIdx.x, ty = threadIdx.y;
#pragma unroll
  for (int i = 0; i < 4; ++i)
    t[ty + i * 8][tx] = W[(size_t)(by + ty + i * 8) * DDM + bx + tx];
  __syncthreads();
#pragma unroll
  for (int i = 0; i < 4; ++i)
    Wt[(size_t)(bx + ty + i * 8) * DDM + by + tx] = (f16)t[tx][ty + i * 8];
}

// ---------------------------------------------------------------------------
// GEMM: C[M,N] = A[M,K] * Bt[N,K]^T + bias.  f16 MFMA, fp32 accum.
// 128x128 tile, 256 thr (4 waves 2x2), BK=64, SINGLE-buffer (32KB LDS ->
// 5 blocks/CU; implicit wave overlap beats dbuf at this occupancy).
// XOR chunk swizzle via pre-swizzled global source + swizzled ds_read.
// mode 0: fp32 out [M,N].  mode 1: f16 split-heads [B,H,S,64].
// mode 2: f16 V^T split-heads [B,H,64,S].
// ---------------------------------------------------------------------------
__global__ __launch_bounds__(256, 4) void gemm_f16_k(
    const f16* __restrict__ A, const f16* __restrict__ Bt,
    const float* __restrict__ bias, void* __restrict__ out, int mode) {
  __shared__ f16 Al[128 * 64];  // 16KB
  __shared__ f16 Bl[128 * 64];  // 16KB
  const int tid = threadIdx.x;
  const int l = tid & 63, w = tid >> 6;
  const int lr = l & 15, lg = l >> 4;
  const int wr = w >> 1, wc = w & 1;
  const int bm = blockIdx.x << 7, bn = blockIdx.y << 7;

  f32x4 acc[4][4];
#pragma unroll
  for (int m = 0; m < 4; ++m)
#pragma unroll
    for (int n = 0; n < 4; ++n) acc[m][n] = (f32x4){0.f, 0.f, 0.f, 0.f};

  const int srow = tid >> 3;                // 0..31
  const int scol = (tid & 7) ^ (srow & 7);  // pre-swizzled 16B chunk
  const f16* Ap = A + (size_t)(bm + srow) * DDM + scol * 8;
  const f16* Bp = Bt + (size_t)(bn + srow) * DDM + scol * 8;
  const int kx = lr & 7;

  for (int kk = 0; kk < DDM; kk += 64) {
#pragma unroll
    for (int it = 0; it < 4; ++it) {
      GLOAD16(Ap + (size_t)(it * 32) * DDM + kk, Al + (it * 256 + w * 64) * 8);
      GLOAD16(Bp + (size_t)(it * 32) * DDM + kk, Bl + (it * 256 + w * 64) * 8);
    }
    __syncthreads();
#pragma unroll
    for (int kh = 0; kh < 2; ++kh) {
      half8 af[4], bf[4];
#pragma unroll
      for (int m = 0; m < 4; ++m) {
        const int row = wr * 64 + m * 16 + lr;
        af[m] = *reinterpret_cast<const half8*>(
            Al + row * 64 + (((kh * 4 + lg) ^ kx) * 8));
      }
#pragma unroll
      for (int n = 0; n < 4; ++n) {
        const int row = wc * 64 + n * 16 + lr;
        bf[n] = *reinterpret_cast<const half8*>(
            Bl + row * 64 + (((kh * 4 + lg) ^ kx) * 8));
      }
#pragma unroll
      for (int m = 0; m < 4; ++m)
#pragma unroll
        for (int n = 0; n < 4; ++n)
          acc[m][n] = __builtin_amdgcn_mfma_f32_16x16x32_f16(af[m], bf[n],
                                                             acc[m][n], 0, 0, 0);
    }
    __syncthreads();
  }

  // epilogue: D layout col = l&15, row = (l>>4)*4 + r
#pragma unroll
  for (int n = 0; n < 4; ++n) {
    const int gn = bn + wc * 64 + n * 16 + lr;
    const float bv = bias[gn];
#pragma unroll
    for (int m = 0; m < 4; ++m) {
      const int gm0 = bm + wr * 64 + m * 16 + lg * 4;
      if (mode == 2) {
        const int b = gm0 >> 11, s = gm0 & (SS - 1);
        const int h = gn >> 6, d = gn & 63;
        f16x4 o;
#pragma unroll
        for (int r = 0; r < 4; ++r) o[r] = (f16)(acc[m][n][r] + bv);
        *reinterpret_cast<f16x4*>(
            reinterpret_cast<f16*>(out) +
            (((size_t)(b * HH + h) * 64 + d) * SS + s)) = o;
      } else {
#pragma unroll
        for (int r = 0; r < 4; ++r) {
          const int gm = gm0 + r;
          const float v = acc[m][n][r] + bv;
          if (mode == 0) {
            reinterpret_cast<float*>(out)[(size_t)gm * DDM + gn] = v;
          } else {
            const int b = gm >> 11, s = gm & (SS - 1);
            const int h = gn >> 6, d = gn & 63;
            reinterpret_cast<f16*>(
                out)[(((size_t)(b * HH + h) * SS + s) << 6) + d] = (f16)v;
          }
        }
      }
    }
  }
}

// ---------------------------------------------------------------------------
// Flash attention v3: f16 MFMA, fp32 online softmax (exp2 domain),
// Q-tile 128 rows/block (2 16-row fragments per wave), KVBLK=64,
// double-buffered K/V staging via global_load_lds (XOR swizzle),
// mask read direct from global (L2-resident), defer-rescale (T13, THR=0).
// Q: [B*H,S,64]  K: [B*H,S,64]  Vt: [B*H,64,S]  ctx: [B,S,1024] f16.
// ---------------------------------------------------------------------------
__global__ __launch_bounds__(256, 3) void attn_f16_k(
    const f16* __restrict__ Q, const f16* __restrict__ K,
    const f16* __restrict__ Vt, const float* __restrict__ mask,
    f16* __restrict__ ctx) {
  __shared__ f16 Kl[2][64 * 64];   // [key][d], swizzled chunks, 8KB each
  __shared__ f16 Vl[2][64 * 64];   // V^T [d][key], swizzled chunks
  __shared__ f16 Pl[4][32 * 66];   // per-wave P: [q][key], stride 66

  const int tid = threadIdx.x;
  const int l = tid & 63, w = tid >> 6;
  const int lr = l & 15, lg = l >> 4;
  const int qt = blockIdx.x;   // 0..15
  const int bh = blockIdx.y;   // 0..63
  const int b = bh >> 4, h = bh & 15;

  const float LOG2E = 1.44269504f;
  const float NEGML2 = -1e9f * 1.44269504f;

  // Q fragments, pre-scaled by 1/8 (exact in f16). A-frag row = l&15.
  half8 qf[2][2];
  const size_t qbase = (size_t)bh * SS + qt * 128 + w * 32;
#pragma unroll
  for (int m = 0; m < 2; ++m) {
    const size_t qrow = qbase + m * 16 + lr;
#pragma unroll
    for (int hh = 0; hh < 2; ++hh) {
      half8 v = *reinterpret_cast<const half8*>(Q + qrow * 64 + hh * 32 + lg * 8);
#pragma unroll
      for (int j = 0; j < 8; ++j) v[j] = v[j] * (f16)0.125f;
      qf[m][hh] = v;
    }
  }

  float m_s[2][4], l_s[2][4];
  f32x4 oa[2][4];
#pragma unroll
  for (int m = 0; m < 2; ++m)
#pragma unroll
    for (int r = 0; r < 4; ++r) { m_s[m][r] = -1e30f; l_s[m][r] = 0.f; }
#pragma unroll
  for (int m = 0; m < 2; ++m)
#pragma unroll
    for (int n = 0; n < 4; ++n) oa[m][n] = (f32x4){0.f, 0.f, 0.f, 0.f};

  const f16* Kg = K + (size_t)bh * SS * 64;
  const f16* Vg = Vt + (size_t)bh * 64 * SS;
  const float* mrow = mask + (size_t)b * SS;

  const int srow = tid >> 3;                // 0..31
  const int scol = (tid & 7) ^ (srow & 7);
  const int kx = lr & 7;
  f16* Pw = Pl[w];

#define A_STAGE(buf, kt)                                                     \
  do {                                                                       \
    const f16* Kt_ = Kg + (size_t)(kt) * 64 * 64;                            \
    GLOAD16(Kt_ + srow * 64 + scol * 8, &Kl[buf][(w * 64) * 8]);             \
    GLOAD16(Kt_ + (32 + srow) * 64 + scol * 8,                               \
            &Kl[buf][(256 + w * 64) * 8]);                                   \
    const f16* Vr_ = Vg + (size_t)(kt) * 64 + scol * 8;                      \
    GLOAD16(Vr_ + (size_t)srow * SS, &Vl[buf][(w * 64) * 8]);                \
    GLOAD16(Vr_ + (size_t)(32 + srow) * SS, &Vl[buf][(256 + w * 64) * 8]);   \
  } while (0)

  A_STAGE(0, 0);
  __syncthreads();

  for (int kt = 0; kt < 32; ++kt) {
    const int cur = kt & 1;
    if (kt + 1 < 32) A_STAGE(cur ^ 1, kt + 1);  // prefetch in flight

    // mask (pre-scaled to base-2 domain); L2-resident
    float mk[4];
#pragma unroll
    for (int n = 0; n < 4; ++n) mk[n] = mrow[kt * 64 + n * 16 + lr] * NEGML2;

    // S^ = (Q/8 @ K^T)*log2e + mask'   (32 q-rows x 64 keys per wave)
    f32x4 sv[2][4];
#pragma unroll
    for (int n = 0; n < 4; ++n) {
      const int krow = (n * 16 + lr) * 64;
      half8 kf0 = *reinterpret_cast<const half8*>(
          &Kl[cur][krow + ((lg ^ kx) * 8)]);
      half8 kf1 = *reinterpret_cast<const half8*>(
          &Kl[cur][krow + (((4 + lg) ^ kx) * 8)]);
#pragma unroll
      for (int m = 0; m < 2; ++m) {
        f32x4 s = (f32x4){0.f, 0.f, 0.f, 0.f};
        s = __builtin_amdgcn_mfma_f32_16x16x32_f16(qf[m][0], kf0, s, 0, 0, 0);
        s = __builtin_amdgcn_mfma_f32_16x16x32_f16(qf[m][1], kf1, s, 0, 0, 0);
#pragma unroll
        for (int r = 0; r < 4; ++r) sv[m][n][r] = fmaf(s[r], LOG2E, mk[n]);
      }
    }

    // tile max per q-row (reduce over n, then the 16 lr lanes)
    float mx[2][4];
    bool need = false;
#pragma unroll
    for (int m = 0; m < 2; ++m)
#pragma unroll
      for (int r = 0; r < 4; ++r) {
        float t0 = fmaxf(fmaxf(sv[m][0][r], sv[m][1][r]),
                         fmaxf(sv[m][2][r], sv[m][3][r]));
        t0 = fmaxf(t0, __shfl_xor(t0, 1));
        t0 = fmaxf(t0, __shfl_xor(t0, 2));
        t0 = fmaxf(t0, __shfl_xor(t0, 4));
        t0 = fmaxf(t0, __shfl_xor(t0, 8));
        mx[m][r] = t0;
        need |= (t0 > m_s[m][r]);
      }
    if (__any(need)) {  // rescale only when a running max grows (rare)
#pragma unroll
      for (int m = 0; m < 2; ++m)
#pragma unroll
        for (int r = 0; r < 4; ++r) {
          const float mn = fmaxf(m_s[m][r], mx[m][r]);
          const float corr = exp2f(m_s[m][r] - mn);
          l_s[m][r] *= corr;
          m_s[m][r] = mn;
#pragma unroll
          for (int n = 0; n < 4; ++n) oa[m][n][r] *= corr;
        }
    }

    // p = exp2(sv - m), row-sum, stash P to per-wave LDS
#pragma unroll
    for (int m = 0; m < 2; ++m)
#pragma unroll
      for (int r = 0; r < 4; ++r) {
        float sum = 0.f;
#pragma unroll
        for (int n = 0; n < 4; ++n) {
          const float p = exp2f(sv[m][n][r] - m_s[m][r]);
          sum += p;
          Pw[(m * 16 + lg * 4 + r) * 66 + n * 16 + lr] = (f16)p;
        }
        sum += __shfl_xor(sum, 1);
        sum += __shfl_xor(sum, 2);
        sum += __shfl_xor(sum, 4);
        sum += __shfl_xor(sum, 8);
        l_s[m][r] += sum;
      }

    // ctx += P @ V
    half8 pa[2][2];
#pragma unroll
    for (int m = 0; m < 2; ++m)
#pragma unroll
      for (int hh = 0; hh < 2; ++hh)
        pa[m][hh] = *reinterpret_cast<const half8*>(
            Pw + (m * 16 + lr) * 66 + hh * 32 + lg * 8);
#pragma unroll
    for (int n = 0; n < 4; ++n) {
      const int vrow = (n * 16 + lr) * 64;
      half8 vf0 = *reinterpret_cast<const half8*>(
          &Vl[cur][vrow + ((lg ^ kx) * 8)]);
      half8 vf1 = *reinterpret_cast<const half8*>(
          &Vl[cur][vrow + (((4 + lg) ^ kx) * 8)]);
#pragma unroll
      for (int m = 0; m < 2; ++m) {
        oa[m][n] = __builtin_amdgcn_mfma_f32_16x16x32_f16(pa[m][0], vf0,
                                                          oa[m][n], 0, 0, 0);
        oa[m][n] = __builtin_amdgcn_mfma_f32_16x16x32_f16(pa[m][1], vf1,
                                                          oa[m][n], 0, 0, 0);
      }
    }
    __syncthreads();  // drains prefetch; all waves done with buf[cur]
  }
#undef A_STAGE

  // epilogue: normalize, write ctx [B,S,1024] f16
#pragma unroll
  for (int m = 0; m < 2; ++m)
#pragma unroll
    for (int r = 0; r < 4; ++r) {
      const float inv = 1.0f / l_s[m][r];
      const int s_g = qt * 128 + w * 32 + m * 16 + lg * 4 + r;
#pragma unroll
      for (int n = 0; n < 4; ++n)
        ctx[((size_t)b * SS + s_g) * DDM + h * 64 + n * 16 + lr] =
            (f16)(oa[m][n][r] * inv);
    }
}

// ---------------------------------------------------------------------------
extern "C" void kernel_launch(void* const* d_in, const int* in_sizes, int n_in,
                              void* d_out, int out_size, void* d_ws,
                              size_t ws_size, hipStream_t stream) {
  const float* query = (const float*)d_in[0];
  const float* key   = (const float*)d_in[1];
  const float* value = (const float*)d_in[2];
  const float* mask  = (const float*)d_in[3];
  const float* Wq = (const float*)d_in[4];
  const float* bq = (const float*)d_in[5];
  const float* Wk = (const float*)d_in[6];
  const float* bk = (const float*)d_in[7];
  const float* Wv = (const float*)d_in[8];
  const float* bv = (const float*)d_in[9];
  const float* Wo = (const float*)d_in[10];
  const float* bo = (const float*)d_in[11];
  float* out = (float*)d_out;

  const size_t E = (size_t)MM * DDM;  // 8M elems
  f16* ws = (f16*)d_ws;
  f16* Qh = ws;             // f16 activations
  f16* Kh = Qh + E;
  f16* Vh = Kh + E;
  f16* Wt0 = Vh + E;        // f16 transposed weights [4][1024][1024]
  f16* Wt3 = Wt0 + (size_t)3 * DDM * DDM;
  f16* Qp = Wt0 + (size_t)4 * DDM * DDM;  // [B,H,S,64]
  f16* Kp = Qp + E;                       // [B,H,S,64]
  f16* Vp = Kp + E;                       // [B,H,64,S]  (V^T)
  f16* Ch = Vp + E;                       // attention ctx [B,S,1024]

  const int n4 = (int)(E / 4);
  cvt3_k<<<dim3(1024, 3), 256, 0, stream>>>(query, key, value, Qh, Kh, Vh, n4);
  wtr4_k<<<dim3(32, 32, 4), dim3(32, 8), 0, stream>>>(Wq, Wk, Wv, Wo, Wt0);

  dim3 gg(MM / 128, DDM / 128);  // (64, 8)
  gemm_f16_k<<<gg, 256, 0, stream>>>(Qh, Wt0, bq, Qp, 1);
  gemm_f16_k<<<gg, 256, 0, stream>>>(Kh, Wt0 + (size_t)DDM * DDM, bk, Kp, 1);
  gemm_f16_k<<<gg, 256, 0, stream>>>(Vh, Wt0 + (size_t)2 * DDM * DDM, bv, Vp, 2);
  attn_f16_k<<<dim3(SS / 128, BB * HH), 256, 0, stream>>>(Qp, Kp, Vp, mask, Ch);
  gemm_f16_k<<<gg, 256, 0, stream>>>(Ch, Wt3, bo, out, 0);
}